// Round 19
// baseline (114.474 us; speedup 1.0000x reference)
//
#include <hip/hip_runtime.h>
#include <stdint.h>

#define N_CAND 25200
#define NB 16
#define ROW 85
#define TK 1024
#define MAXDET 300
#define CAP 2048
#define BITS_LO 0x3E800000u
#define CHUNK 6300        // N_CAND / 4

typedef unsigned long long u64;
typedef unsigned int u32;

struct u64x2 { u64 x, y; };

static __device__ __forceinline__ u64 u64min(u64 a, u64 b) { return a < b ? a : b; }
static __device__ __forceinline__ u64 u64max(u64 a, u64 b) { return a > b ? a : b; }

// ---------------- K1: score + key; global->LDS direct staging (R9-verified) ----------------
__global__ __launch_bounds__(256, 8) void score_kernel(const float* __restrict__ pred,
                                                       u64* __restrict__ keys)
{
#pragma clang fp contract(off)
    __shared__ float tile[64 * ROW];                 // 21.76 KB
    const int tid = threadIdx.x;
    const int row0 = blockIdx.x * 64;                // 6300 blocks
    const float4* src = (const float4*)(pred + (size_t)row0 * ROW);
    float4* dst = (float4*)tile;
#pragma unroll
    for (int i = 0; i < 6; ++i) {
        int idx = tid + (i << 8);
        if (idx < (64 * ROW) / 4) {
            __builtin_amdgcn_global_load_lds(
                (const __attribute__((address_space(1))) void*)(src + idx),
                (__attribute__((address_space(3))) void*)(dst + idx),
                16, 0, 0);
        }
    }
    __syncthreads();

    const int r = tid >> 2, sub = tid & 3;
    const float* rowp = tile + r * ROW;
    const float obj = rowp[4];
    const int base = 5 + sub * 20;
    float bv = obj * rowp[base];                     // products, exactly like reference
    int bi = base - 5;
#pragma unroll
    for (int c = 1; c < 20; ++c) {
        float p = obj * rowp[base + c];
        if (p > bv) { bv = p; bi = base - 5 + c; }   // strict > : first occurrence
    }
#pragma unroll
    for (int off = 1; off <= 2; off <<= 1) {
        float ov = __shfl_xor(bv, off, 64);
        int   oi = __shfl_xor(bi, off, 64);
        if (ov > bv || (ov == bv && oi < bi)) { bv = ov; bi = oi; }
    }
    if (sub == 0) {
        int w = row0 + r;
        u32 n = (u32)w % N_CAND;
        u64 key = 0;
        if (obj > 0.25f && bv > 0.25f)
            key = ((u64)__float_as_uint(bv) << 32) | (((u64)(25199u - n)) << 7) | (u32)bi;
        keys[w] = key;                               // desc sort => conf desc, n asc (ties)
    }
}

// ---------------- K2a: wide per-chunk histogram (4 chunks x 16 batches, LDS-private) ----------------
__global__ __launch_bounds__(256) void hist_kernel(const u64* __restrict__ keys,
                                                   u32* __restrict__ ghist)
{
    __shared__ u32 h[2048];
    const int tid = threadIdx.x;
    const int c = blockIdx.x;                        // chunk 0..3
    const int b = blockIdx.y;                        // batch
    for (int i = tid; i < 2048; i += 256) h[i] = 0;
    __syncthreads();
    const u64x2* src = (const u64x2*)(keys + (size_t)b * N_CAND + c * CHUNK);  // 16B-aligned
    for (int p = tid; p < CHUNK / 2; p += 256) {
        u64x2 kk = src[p];
        u32 bits0 = (u32)(kk.x >> 32);
        if (bits0) {
            int bin = (int)((bits0 - BITS_LO) >> 13);
            bin = bin < 0 ? 0 : (bin > 2047 ? 2047 : bin);
            atomicAdd(&h[bin], 1u);
        }
        u32 bits1 = (u32)(kk.y >> 32);
        if (bits1) {
            int bin = (int)((bits1 - BITS_LO) >> 13);
            bin = bin < 0 ? 0 : (bin > 2047 ? 2047 : bin);
            atomicAdd(&h[bin], 1u);
        }
    }
    __syncthreads();
    u32* dst = ghist + ((size_t)((b << 2) + c) << 11);
    for (int i = tid; i < 2048; i += 256) dst[i] = h[i];
}

// ---------------- K2b: hist-sum + suffix-sum + EXACT-RANK gather + per-bin wave sort -> SoA ----------------
__global__ __launch_bounds__(1024) void topk_kernel(const float* __restrict__ pred,
                                                    const u64* __restrict__ keys,
                                                    const u32* __restrict__ ghist,
                                                    float4* __restrict__ soaA,
                                                    float4* __restrict__ soaB)
{
#pragma clang fp contract(off)
    __shared__ u64 sbuf[CAP];                        // 16 KB -- rank-ordered keys
    __shared__ u32 histA[2048];                      // 8 KB
    __shared__ u32 histB[2048];                      // 8 KB
    __shared__ u32 s_t;
    __shared__ int s_fb;

    const int tid = threadIdx.x;
    const int b = blockIdx.x;
    const u64* kb = keys + (size_t)b * N_CAND;
    const u64x2* kb2 = (const u64x2*)kb;             // 16B-aligned
    const float* pb = pred + (size_t)b * N_CAND * ROW;

    for (int i = tid; i < CAP; i += 1024) sbuf[i] = 0ull;
    if (tid == 0) { s_t = 0; s_fb = 0; }

    // Phase A: sum the 4 precomputed chunk histograms (binning math identical to before)
    for (int i = tid; i < 2048; i += 1024) {
        u32 s = 0;
#pragma unroll
        for (int c = 0; c < 4; ++c)
            s += ghist[((size_t)((b << 2) + c) << 11) + i];
        histA[i] = s;
    }
    __syncthreads();

    // Phase A2: parallel suffix sum (Hillis-Steele, 11 passes); srcp ends = suffix
    u32* srcp = histA; u32* dstp = histB;
    for (int step = 1; step < 2048; step <<= 1) {
        for (int i = tid; i < 2048; i += 1024)
            dstp[i] = srcp[i] + ((i + step < 2048) ? srcp[i + step] : 0u);
        __syncthreads();
        u32* t = srcp; srcp = dstp; dstp = t;
    }
    for (int i = tid; i < 2048; i += 1024) {
        u32 S = srcp[i];
        if (S >= TK && (i == 2047 || srcp[i + 1] < TK)) s_t = (u32)i;
    }
    __syncthreads();
    const int t = (int)s_t;
    const u32 thr = BITS_LO + ((u32)t << 13);

    // cursors (rank base per bin) in dstp; detect oversized bins -> fallback
    for (int i = tid; i < 2048; i += 1024) {
        u32 base = (i < 2047) ? srcp[i + 1] : 0u;
        dstp[i] = base;
        if (i >= t && (srcp[i] - base) > 64u) s_fb = 1;   // benign race (same value)
    }
    __syncthreads();

    // Phase B: gather at EXACT final rank, 2 keys/thread/iter
    for (int p = tid; p < N_CAND / 2; p += 1024) {
        u64x2 kk = kb2[p];
        u32 bits0 = (u32)(kk.x >> 32);
        if (bits0 >= thr) {
            int bin = (int)((bits0 - BITS_LO) >> 13);
            bin = bin < 0 ? 0 : (bin > 2047 ? 2047 : bin);
            u32 pos = atomicAdd(&dstp[bin], 1u);
            if (pos < CAP) sbuf[pos] = kk.x;
        }
        u32 bits1 = (u32)(kk.y >> 32);
        if (bits1 >= thr) {
            int bin = (int)((bits1 - BITS_LO) >> 13);
            bin = bin < 0 ? 0 : (bin > 2047 ? 2047 : bin);
            u32 pos = atomicAdd(&dstp[bin], 1u);
            if (pos < CAP) sbuf[pos] = kk.y;
        }
    }
    __syncthreads();

    if (!s_fb) {
        // Phase C': per-bin 64-wide wave bitonic, DESC by full u64 key (barrier-free)
        const int wave = tid >> 6, lane = tid & 63;
        for (int bin = t + wave; bin < 2048; bin += 16) {
            u32 base = (bin < 2047) ? srcp[bin + 1] : 0u;
            u32 end = srcp[bin]; if (end > CAP) end = CAP;
            if (end <= base + 1) continue;
            u32 cnt_b = end - base;
            u64 v = (lane < (int)cnt_b) ? sbuf[base + lane] : 0ull;
#pragma unroll
            for (int k2 = 2; k2 <= 64; k2 <<= 1) {
                for (int j = k2 >> 1; j > 0; j >>= 1) {
                    u64 p = __shfl_xor(v, j, 64);
                    const bool up = ((lane & k2) == 0);
                    const bool low = ((lane & j) == 0);
                    v = (up == low) ? u64max(v, p) : u64min(v, p);
                }
            }
            if (lane < (int)cnt_b) sbuf[base + lane] = v;
        }
        __syncthreads();
    } else {
        // fallback: verified block-wide hybrid bitonic sort ASC (extract reversed)
        const int E0 = tid << 1;
        u64 e0 = sbuf[E0], e1 = sbuf[E0 + 1];
        for (int k = 2; k <= CAP; k <<= 1) {
            for (int j = k >> 1; j > 0; j >>= 1) {
                const bool asc = ((E0 & k) == 0);
                if (j >= 128) {
                    __syncthreads();
                    sbuf[E0] = e0; sbuf[E0 + 1] = e1;
                    __syncthreads();
                    u64 p0 = sbuf[E0 ^ j], p1 = sbuf[(E0 + 1) ^ j];
                    const bool low = ((E0 & j) == 0);
                    e0 = (asc == low) ? u64min(e0, p0) : u64max(e0, p0);
                    e1 = (asc == low) ? u64min(e1, p1) : u64max(e1, p1);
                } else if (j >= 2) {
                    const int l = j >> 1;
                    u64 p0 = __shfl_xor(e0, l, 64);
                    u64 p1 = __shfl_xor(e1, l, 64);
                    const bool low = ((E0 & j) == 0);
                    e0 = (asc == low) ? u64min(e0, p0) : u64max(e0, p0);
                    e1 = (asc == low) ? u64min(e1, p1) : u64max(e1, p1);
                } else {
                    u64 mn = u64min(e0, e1), mx = u64max(e0, e1);
                    e0 = asc ? mn : mx;
                    e1 = asc ? mx : mn;
                }
            }
        }
        __syncthreads();
        sbuf[E0] = e0; sbuf[E0 + 1] = e1;
        __syncthreads();
    }

    // Phase D: slot i = rank i (or reversed in fallback); gather boxes, write SoA
    {
        const int i = tid;
        u64 k = sbuf[s_fb ? (CAP - 1 - i) : i];
        u32 bits = (u32)(k >> 32);
        float4 A, Bv;
        if (bits) {
            u32 lo = (u32)k;
            u32 n = 25199u - (lo >> 7);
            float c = (float)(lo & 127u);
            const float* rp = pb + (size_t)n * ROW;
            float x = rp[0], y = rp[1], ww = rp[2], hh = rp[3];
            float hw = ww * 0.5f, hv = hh * 0.5f;
            float x1 = x - hw, y1 = y - hv, x2 = x + hw, y2 = y + hv;
            float offc = c * 4096.0f;
            float area = ((x2 + offc) - (x1 + offc)) * ((y2 + offc) - (y1 + offc));
            A = make_float4(x1, y1, x2, y2);
            Bv = make_float4(area, __uint_as_float(bits), c, 0.0f);
        } else {
            A = make_float4(0.0f, 0.0f, 0.0f, 0.0f);
            Bv = make_float4(0.0f, -1.0f, 0.0f, 0.0f);
        }
        soaA[b * TK + i] = A;
        soaB[b * TK + i] = Bv;
    }
}

// ---------------- K3: suppression bitmask; upper-window words only (R17-verified) ----------------
__global__ __launch_bounds__(512) void mask_kernel(const float4* __restrict__ soaA,
                                                   const float4* __restrict__ soaB,
                                                   u64* __restrict__ masks)
{
#pragma clang fp contract(off)
    __shared__ float qx1[TK], qy1[TK], qx2[TK], qy2[TK], qar[TK];  // 20 KB, b32 conflict-free
    const int tid = threadIdx.x;
    const int b = blockIdx.y;
    const int rbase = blockIdx.x * 32;               // 32 rows/block, gridDim.x = 32
    const int wi = rbase >> 6;                       // window of all rows in this block
    for (int i = tid; i < TK; i += 512) {
        float4 A = soaA[b * TK + i];
        float4 Bv = soaB[b * TK + i];
        float off = Bv.z * 4096.0f;
        qx1[i] = A.x + off; qy1[i] = A.y + off;
        qx2[i] = A.z + off; qy2[i] = A.w + off;
        qar[i] = Bv.x;
    }
    __syncthreads();

    const int wave = tid >> 6, lane = tid & 63;
    for (int rr = 0; rr < 4; ++rr) {
        int i = rbase + (wave << 2) + rr;            // 8 waves x 4 rows = 32 rows
        float px1 = qx1[i], py1 = qy1[i];
        float px2 = qx2[i], py2 = qy2[i];
        float parea = qar[i];
        u64 myword = 0;
        for (int word = wi; word < 16; ++word) {     // words < wi never read downstream
            int j = (word << 6) + lane;              // stride-4B: conflict-free
            float ltx = fmaxf(px1, qx1[j]), lty = fmaxf(py1, qy1[j]);
            float rbx = fminf(px2, qx2[j]), rby = fminf(py2, qy2[j]);
            float w2 = fmaxf(rbx - ltx, 0.0f), h2 = fmaxf(rby - lty, 0.0f);
            float inter = w2 * h2;
            float iou = inter / (parea + qar[j] - inter + 1e-9f);
            u64 m = __ballot(iou > 0.45f);
            if (lane == word) myword = m;
        }
        if (lane >= wi && lane < 16) masks[((size_t)(b * TK + i) << 4) + lane] = myword;
    }
}

// ---------------- K4: sweep; batched nv-count loads + 8-row prefetch chain (R18-verified) ----------------
__global__ __launch_bounds__(64) void sweep_kernel(const float4* __restrict__ soaA,
                                                   const float4* __restrict__ soaB,
                                                   const u64* __restrict__ masks,
                                                   float* __restrict__ out)
{
#pragma clang fp contract(off)
    __shared__ int sel[MAXDET];
    const int lane = threadIdx.x;
    const int b = blockIdx.x;
    const u64* mb = masks + ((size_t)(b * TK) << 4);

    // nv-count: issue all 16 independent loads first, then ballot
    float sv[16];
#pragma unroll
    for (int k = 0; k < 16; ++k)
        sv[k] = soaB[b * TK + (k << 6) + lane].y;
    int nv = TK;
    bool found = false;
#pragma unroll
    for (int k = 0; k < 16; ++k) {
        u64 m = __ballot(sv[k] > 0.0f);
        if (!found && m != ~0ull) { nv = (k << 6) + (int)__builtin_ctzll(~m); found = true; }
    }

    u64 removed = 0;                                 // lane w (w<16) owns word w
    int nsel = 0;
    bool done = (nv == 0);
    const int li = lane & 15;

    u64 cur[8], nxt[8];
#pragma unroll
    for (int r = 0; r < 8; ++r) cur[r] = mb[((size_t)r << 4) + li];

    for (int c = 0; c < 128 && !done; ++c) {
        int nb0 = (c + 1) << 3;
#pragma unroll
        for (int r = 0; r < 8; ++r) {                // prefetch next chunk
            int i2 = nb0 + r; if (i2 > TK - 1) i2 = TK - 1;
            nxt[r] = mb[((size_t)i2 << 4) + li];
        }
#pragma unroll
        for (int r = 0; r < 8; ++r) {
            int i = (c << 3) + r;
            if (!done && i < nv) {
                u64 wv = __shfl(removed, i >> 6, 64);
                if (!((wv >> (i & 63)) & 1ull)) {    // alive -> select
                    if (lane == 0) sel[nsel] = i;
                    removed |= cur[r];
                    ++nsel;
                    if (nsel == MAXDET) done = true;
                }
            } else if (i >= nv) done = true;
        }
#pragma unroll
        for (int r = 0; r < 8; ++r) cur[r] = nxt[r];
    }
    __syncthreads();

    // epilogue: scale_coords (gain=0.5, pad=(0,140)) + write 300 rows
    for (int r = lane; r < MAXDET; r += 64) {
        float* o = out + ((size_t)b * MAXDET + r) * 6;
        if (r < nsel) {
            int p = sel[r];
            float4 A = soaA[b * TK + p];
            float4 Bv = soaB[b * TK + p];
            float X1 = (A.x - 0.0f) / 0.5f;
            float Y1 = (A.y - 140.0f) / 0.5f;
            float X2 = (A.z - 0.0f) / 0.5f;
            float Y2 = (A.w - 140.0f) / 0.5f;
            X1 = fminf(fmaxf(X1, 0.0f), 1280.0f);
            Y1 = fminf(fmaxf(Y1, 0.0f), 720.0f);
            X2 = fminf(fmaxf(X2, 0.0f), 1280.0f);
            Y2 = fminf(fmaxf(Y2, 0.0f), 720.0f);
            o[0] = X1; o[1] = Y1; o[2] = X2; o[3] = Y2;
            o[4] = Bv.y; o[5] = Bv.z;
        } else {
            o[0] = 0.0f; o[1] = 0.0f; o[2] = 0.0f;
            o[3] = 0.0f; o[4] = 0.0f; o[5] = 0.0f;
        }
    }
}

extern "C" void kernel_launch(void* const* d_in, const int* in_sizes, int n_in,
                              void* d_out, int out_size, void* d_ws, size_t ws_size,
                              hipStream_t stream)
{
    const float* pred = (const float*)d_in[0];
    float* out = (float*)d_out;

    // workspace layout (high-water ~4.27 MB; ws poison shows ws_size ~548 MB):
    //   [0, 3,225,600)          keys (u64 x 403200)  -- dead after K2b
    //   [0, 2,097,152)          masks (u64 x 262144) -- aliases keys, written by K3 after K2b
    //   [3,225,600, +262,144)   soaA (float4 x 16384)
    //   [3,487,744, +262,144)   soaB (float4 x 16384)
    //   [3,749,888, +524,288)   ghist (u32 x 16 x 4 x 2048)
    u64* keys = (u64*)d_ws;
    u64* masks = (u64*)d_ws;
    float4* soaA = (float4*)((char*)d_ws + 3225600);
    float4* soaB = (float4*)((char*)d_ws + 3225600 + 262144);
    u32* ghist = (u32*)((char*)d_ws + 3749888);

    score_kernel<<<(NB * N_CAND) / 64, 256, 0, stream>>>(pred, keys);
    hist_kernel<<<dim3(4, NB), 256, 0, stream>>>(keys, ghist);
    topk_kernel<<<NB, 1024, 0, stream>>>(pred, keys, ghist, soaA, soaB);
    mask_kernel<<<dim3(32, NB), 512, 0, stream>>>(soaA, soaB, masks);
    sweep_kernel<<<NB, 64, 0, stream>>>(soaA, soaB, masks, out);
}

// Round 20
// 109.511 us; speedup vs baseline: 1.0453x; 1.0453x over previous
//
#include <hip/hip_runtime.h>
#include <stdint.h>

#define N_CAND 25200
#define NB 16
#define ROW 85
#define TK 1024
#define MAXDET 300
#define CAP 2048
#define BITS_LO 0x3E800000u

typedef unsigned long long u64;
typedef unsigned int u32;

struct u64x2 { u64 x, y; };

static __device__ __forceinline__ u64 u64min(u64 a, u64 b) { return a < b ? a : b; }
static __device__ __forceinline__ u64 u64max(u64 a, u64 b) { return a > b ? a : b; }

// ---------------- K1: score + key; global->LDS direct staging (R9-verified) ----------------
__global__ __launch_bounds__(256, 8) void score_kernel(const float* __restrict__ pred,
                                                       u64* __restrict__ keys)
{
#pragma clang fp contract(off)
    __shared__ float tile[64 * ROW];                 // 21.76 KB
    const int tid = threadIdx.x;
    const int row0 = blockIdx.x * 64;                // 6300 blocks
    const float4* src = (const float4*)(pred + (size_t)row0 * ROW);
    float4* dst = (float4*)tile;
#pragma unroll
    for (int i = 0; i < 6; ++i) {
        int idx = tid + (i << 8);
        if (idx < (64 * ROW) / 4) {
            __builtin_amdgcn_global_load_lds(
                (const __attribute__((address_space(1))) void*)(src + idx),
                (__attribute__((address_space(3))) void*)(dst + idx),
                16, 0, 0);
        }
    }
    __syncthreads();

    const int r = tid >> 2, sub = tid & 3;
    const float* rowp = tile + r * ROW;
    const float obj = rowp[4];
    const int base = 5 + sub * 20;
    float bv = obj * rowp[base];                     // products, exactly like reference
    int bi = base - 5;
#pragma unroll
    for (int c = 1; c < 20; ++c) {
        float p = obj * rowp[base + c];
        if (p > bv) { bv = p; bi = base - 5 + c; }   // strict > : first occurrence
    }
#pragma unroll
    for (int off = 1; off <= 2; off <<= 1) {
        float ov = __shfl_xor(bv, off, 64);
        int   oi = __shfl_xor(bi, off, 64);
        if (ov > bv || (ov == bv && oi < bi)) { bv = ov; bi = oi; }
    }
    if (sub == 0) {
        int w = row0 + r;
        u32 n = (u32)w % N_CAND;
        u64 key = 0;
        if (obj > 0.25f && bv > 0.25f)
            key = ((u64)__float_as_uint(bv) << 32) | (((u64)(25199u - n)) << 7) | (u32)bi;
        keys[w] = key;                               // desc sort => conf desc, n asc (ties)
    }
}

// ---------------- K2: vectorized key passes + suffix-sum + EXACT-RANK gather + per-bin sort ----------------
__global__ __launch_bounds__(1024) void topk_kernel(const float* __restrict__ pred,
                                                    const u64* __restrict__ keys,
                                                    float4* __restrict__ soaA,
                                                    float4* __restrict__ soaB)
{
#pragma clang fp contract(off)
    __shared__ u64 sbuf[CAP];                        // 16 KB -- rank-ordered keys
    __shared__ u32 histA[2048];                      // 8 KB
    __shared__ u32 histB[2048];                      // 8 KB
    __shared__ u32 s_t;
    __shared__ int s_fb;

    const int tid = threadIdx.x;
    const int b = blockIdx.x;
    const u64* kb = keys + (size_t)b * N_CAND;
    const u64x2* kb2 = (const u64x2*)kb;             // 16B-aligned (b*201600 % 16 == 0)
    const float* pb = pred + (size_t)b * N_CAND * ROW;

    for (int i = tid; i < 2048; i += 1024) histA[i] = 0;
    for (int i = tid; i < CAP; i += 1024) sbuf[i] = 0ull;
    if (tid == 0) { s_t = 0; s_fb = 0; }
    __syncthreads();

    // Phase A: histogram of conf bits, 2 keys/thread/iter (N_CAND even -> 12600 pairs)
    for (int p = tid; p < N_CAND / 2; p += 1024) {
        u64x2 kk = kb2[p];
        u32 bits0 = (u32)(kk.x >> 32);
        if (bits0) {
            int bin = (int)((bits0 - BITS_LO) >> 13);
            bin = bin < 0 ? 0 : (bin > 2047 ? 2047 : bin);
            atomicAdd(&histA[bin], 1u);
        }
        u32 bits1 = (u32)(kk.y >> 32);
        if (bits1) {
            int bin = (int)((bits1 - BITS_LO) >> 13);
            bin = bin < 0 ? 0 : (bin > 2047 ? 2047 : bin);
            atomicAdd(&histA[bin], 1u);
        }
    }
    __syncthreads();

    // Phase A2: parallel suffix sum (Hillis-Steele, 11 passes); srcp ends = suffix
    u32* srcp = histA; u32* dstp = histB;
    for (int step = 1; step < 2048; step <<= 1) {
        for (int i = tid; i < 2048; i += 1024)
            dstp[i] = srcp[i] + ((i + step < 2048) ? srcp[i + step] : 0u);
        __syncthreads();
        u32* t = srcp; srcp = dstp; dstp = t;
    }
    for (int i = tid; i < 2048; i += 1024) {
        u32 S = srcp[i];
        if (S >= TK && (i == 2047 || srcp[i + 1] < TK)) s_t = (u32)i;
    }
    __syncthreads();
    const int t = (int)s_t;
    const u32 thr = BITS_LO + ((u32)t << 13);

    // cursors (rank base per bin) in dstp; detect oversized bins -> fallback
    for (int i = tid; i < 2048; i += 1024) {
        u32 base = (i < 2047) ? srcp[i + 1] : 0u;
        dstp[i] = base;
        if (i >= t && (srcp[i] - base) > 64u) s_fb = 1;   // benign race (same value)
    }
    __syncthreads();

    // Phase B: gather at EXACT final rank, 2 keys/thread/iter
    for (int p = tid; p < N_CAND / 2; p += 1024) {
        u64x2 kk = kb2[p];
        u32 bits0 = (u32)(kk.x >> 32);
        if (bits0 >= thr) {
            int bin = (int)((bits0 - BITS_LO) >> 13);
            bin = bin < 0 ? 0 : (bin > 2047 ? 2047 : bin);
            u32 pos = atomicAdd(&dstp[bin], 1u);
            if (pos < CAP) sbuf[pos] = kk.x;
        }
        u32 bits1 = (u32)(kk.y >> 32);
        if (bits1 >= thr) {
            int bin = (int)((bits1 - BITS_LO) >> 13);
            bin = bin < 0 ? 0 : (bin > 2047 ? 2047 : bin);
            u32 pos = atomicAdd(&dstp[bin], 1u);
            if (pos < CAP) sbuf[pos] = kk.y;
        }
    }
    __syncthreads();

    if (!s_fb) {
        // Phase C': per-bin 64-wide wave bitonic, DESC by full u64 key (barrier-free)
        const int wave = tid >> 6, lane = tid & 63;
        for (int bin = t + wave; bin < 2048; bin += 16) {
            u32 base = (bin < 2047) ? srcp[bin + 1] : 0u;
            u32 end = srcp[bin]; if (end > CAP) end = CAP;
            if (end <= base + 1) continue;
            u32 cnt_b = end - base;
            u64 v = (lane < (int)cnt_b) ? sbuf[base + lane] : 0ull;
#pragma unroll
            for (int k2 = 2; k2 <= 64; k2 <<= 1) {
                for (int j = k2 >> 1; j > 0; j >>= 1) {
                    u64 p = __shfl_xor(v, j, 64);
                    const bool up = ((lane & k2) == 0);
                    const bool low = ((lane & j) == 0);
                    v = (up == low) ? u64max(v, p) : u64min(v, p);
                }
            }
            if (lane < (int)cnt_b) sbuf[base + lane] = v;
        }
        __syncthreads();
    } else {
        // fallback: verified block-wide hybrid bitonic sort ASC (extract reversed)
        const int E0 = tid << 1;
        u64 e0 = sbuf[E0], e1 = sbuf[E0 + 1];
        for (int k = 2; k <= CAP; k <<= 1) {
            for (int j = k >> 1; j > 0; j >>= 1) {
                const bool asc = ((E0 & k) == 0);
                if (j >= 128) {
                    __syncthreads();
                    sbuf[E0] = e0; sbuf[E0 + 1] = e1;
                    __syncthreads();
                    u64 p0 = sbuf[E0 ^ j], p1 = sbuf[(E0 + 1) ^ j];
                    const bool low = ((E0 & j) == 0);
                    e0 = (asc == low) ? u64min(e0, p0) : u64max(e0, p0);
                    e1 = (asc == low) ? u64min(e1, p1) : u64max(e1, p1);
                } else if (j >= 2) {
                    const int l = j >> 1;
                    u64 p0 = __shfl_xor(e0, l, 64);
                    u64 p1 = __shfl_xor(e1, l, 64);
                    const bool low = ((E0 & j) == 0);
                    e0 = (asc == low) ? u64min(e0, p0) : u64max(e0, p0);
                    e1 = (asc == low) ? u64min(e1, p1) : u64max(e1, p1);
                } else {
                    u64 mn = u64min(e0, e1), mx = u64max(e0, e1);
                    e0 = asc ? mn : mx;
                    e1 = asc ? mx : mn;
                }
            }
        }
        __syncthreads();
        sbuf[E0] = e0; sbuf[E0 + 1] = e1;
        __syncthreads();
    }

    // Phase D: slot i = rank i (or reversed in fallback); gather boxes, write SoA
    {
        const int i = tid;
        u64 k = sbuf[s_fb ? (CAP - 1 - i) : i];
        u32 bits = (u32)(k >> 32);
        float4 A, Bv;
        if (bits) {
            u32 lo = (u32)k;
            u32 n = 25199u - (lo >> 7);
            float c = (float)(lo & 127u);
            const float* rp = pb + (size_t)n * ROW;
            float x = rp[0], y = rp[1], ww = rp[2], hh = rp[3];
            float hw = ww * 0.5f, hv = hh * 0.5f;
            float x1 = x - hw, y1 = y - hv, x2 = x + hw, y2 = y + hv;
            float offc = c * 4096.0f;
            float area = ((x2 + offc) - (x1 + offc)) * ((y2 + offc) - (y1 + offc));
            A = make_float4(x1, y1, x2, y2);
            Bv = make_float4(area, __uint_as_float(bits), c, 0.0f);
        } else {
            A = make_float4(0.0f, 0.0f, 0.0f, 0.0f);
            Bv = make_float4(0.0f, -1.0f, 0.0f, 0.0f);
        }
        soaA[b * TK + i] = A;
        soaB[b * TK + i] = Bv;
    }
}

// ---------------- K3: suppression bitmask; upper-window words only (R17-verified) ----------------
__global__ __launch_bounds__(512) void mask_kernel(const float4* __restrict__ soaA,
                                                   const float4* __restrict__ soaB,
                                                   u64* __restrict__ masks)
{
#pragma clang fp contract(off)
    __shared__ float qx1[TK], qy1[TK], qx2[TK], qy2[TK], qar[TK];  // 20 KB, b32 conflict-free
    const int tid = threadIdx.x;
    const int b = blockIdx.y;
    const int rbase = blockIdx.x * 32;               // 32 rows/block, gridDim.x = 32
    const int wi = rbase >> 6;                       // window of all rows in this block
    for (int i = tid; i < TK; i += 512) {
        float4 A = soaA[b * TK + i];
        float4 Bv = soaB[b * TK + i];
        float off = Bv.z * 4096.0f;
        qx1[i] = A.x + off; qy1[i] = A.y + off;
        qx2[i] = A.z + off; qy2[i] = A.w + off;
        qar[i] = Bv.x;
    }
    __syncthreads();

    const int wave = tid >> 6, lane = tid & 63;
    for (int rr = 0; rr < 4; ++rr) {
        int i = rbase + (wave << 2) + rr;            // 8 waves x 4 rows = 32 rows
        float px1 = qx1[i], py1 = qy1[i];
        float px2 = qx2[i], py2 = qy2[i];
        float parea = qar[i];
        u64 myword = 0;
        for (int word = wi; word < 16; ++word) {     // words < wi never read downstream
            int j = (word << 6) + lane;              // stride-4B: conflict-free
            float ltx = fmaxf(px1, qx1[j]), lty = fmaxf(py1, qy1[j]);
            float rbx = fminf(px2, qx2[j]), rby = fminf(py2, qy2[j]);
            float w2 = fmaxf(rbx - ltx, 0.0f), h2 = fmaxf(rby - lty, 0.0f);
            float inter = w2 * h2;
            float iou = inter / (parea + qar[j] - inter + 1e-9f);
            u64 m = __ballot(iou > 0.45f);
            if (lane == word) myword = m;
        }
        if (lane >= wi && lane < 16) masks[((size_t)(b * TK + i) << 4) + lane] = myword;
    }
}

// ---------------- K4: sweep; batched nv-count loads + 8-row prefetch chain (R18-verified) ----------------
__global__ __launch_bounds__(64) void sweep_kernel(const float4* __restrict__ soaA,
                                                   const float4* __restrict__ soaB,
                                                   const u64* __restrict__ masks,
                                                   float* __restrict__ out)
{
#pragma clang fp contract(off)
    __shared__ int sel[MAXDET];
    const int lane = threadIdx.x;
    const int b = blockIdx.x;
    const u64* mb = masks + ((size_t)(b * TK) << 4);

    // nv-count: issue all 16 independent loads first (one latency window), then ballot
    float sv[16];
#pragma unroll
    for (int k = 0; k < 16; ++k)
        sv[k] = soaB[b * TK + (k << 6) + lane].y;
    int nv = TK;
    bool found = false;
#pragma unroll
    for (int k = 0; k < 16; ++k) {
        u64 m = __ballot(sv[k] > 0.0f);
        if (!found && m != ~0ull) { nv = (k << 6) + (int)__builtin_ctzll(~m); found = true; }
    }

    u64 removed = 0;                                 // lane w (w<16) owns word w
    int nsel = 0;
    bool done = (nv == 0);
    const int li = lane & 15;

    u64 cur[8], nxt[8];
#pragma unroll
    for (int r = 0; r < 8; ++r) cur[r] = mb[((size_t)r << 4) + li];

    for (int c = 0; c < 128 && !done; ++c) {
        int nb0 = (c + 1) << 3;
#pragma unroll
        for (int r = 0; r < 8; ++r) {                // prefetch next chunk
            int i2 = nb0 + r; if (i2 > TK - 1) i2 = TK - 1;
            nxt[r] = mb[((size_t)i2 << 4) + li];
        }
#pragma unroll
        for (int r = 0; r < 8; ++r) {
            int i = (c << 3) + r;
            if (!done && i < nv) {
                u64 wv = __shfl(removed, i >> 6, 64);
                if (!((wv >> (i & 63)) & 1ull)) {    // alive -> select
                    if (lane == 0) sel[nsel] = i;
                    removed |= cur[r];
                    ++nsel;
                    if (nsel == MAXDET) done = true;
                }
            } else if (i >= nv) done = true;
        }
#pragma unroll
        for (int r = 0; r < 8; ++r) cur[r] = nxt[r];
    }
    __syncthreads();

    // epilogue: scale_coords (gain=0.5, pad=(0,140)) + write 300 rows
    for (int r = lane; r < MAXDET; r += 64) {
        float* o = out + ((size_t)b * MAXDET + r) * 6;
        if (r < nsel) {
            int p = sel[r];
            float4 A = soaA[b * TK + p];
            float4 Bv = soaB[b * TK + p];
            float X1 = (A.x - 0.0f) / 0.5f;
            float Y1 = (A.y - 140.0f) / 0.5f;
            float X2 = (A.z - 0.0f) / 0.5f;
            float Y2 = (A.w - 140.0f) / 0.5f;
            X1 = fminf(fmaxf(X1, 0.0f), 1280.0f);
            Y1 = fminf(fmaxf(Y1, 0.0f), 720.0f);
            X2 = fminf(fmaxf(X2, 0.0f), 1280.0f);
            Y2 = fminf(fmaxf(Y2, 0.0f), 720.0f);
            o[0] = X1; o[1] = Y1; o[2] = X2; o[3] = Y2;
            o[4] = Bv.y; o[5] = Bv.z;
        } else {
            o[0] = 0.0f; o[1] = 0.0f; o[2] = 0.0f;
            o[3] = 0.0f; o[4] = 0.0f; o[5] = 0.0f;
        }
    }
}

extern "C" void kernel_launch(void* const* d_in, const int* in_sizes, int n_in,
                              void* d_out, int out_size, void* d_ws, size_t ws_size,
                              hipStream_t stream)
{
    const float* pred = (const float*)d_in[0];
    float* out = (float*)d_out;

    // workspace layout (high-water 3.75 MB):
    //   [0, 3,225,600)          keys (u64 x 403200)  -- dead after K2
    //   [0, 2,097,152)          masks (u64 x 262144) -- aliases keys, written by K3 after K2
    //   [3,225,600, +262,144)   soaA (float4 x 16384)
    //   [3,487,744, +262,144)   soaB (float4 x 16384)
    u64* keys = (u64*)d_ws;
    u64* masks = (u64*)d_ws;
    float4* soaA = (float4*)((char*)d_ws + 3225600);
    float4* soaB = (float4*)((char*)d_ws + 3225600 + 262144);

    score_kernel<<<(NB * N_CAND) / 64, 256, 0, stream>>>(pred, keys);
    topk_kernel<<<NB, 1024, 0, stream>>>(pred, keys, soaA, soaB);
    mask_kernel<<<dim3(32, NB), 512, 0, stream>>>(soaA, soaB, masks);
    sweep_kernel<<<NB, 64, 0, stream>>>(soaA, soaB, masks, out);
}